// Round 4
// baseline (469.282 us; speedup 1.0000x reference)
//
#include <hip/hip_runtime.h>
#include <math.h>

constexpr int NB = 32;
constexpr int NS = 2048;
constexpr int NE = 1024;
constexpr int ND = 1024;

// -------------------------------------------------------------------------
// One dispatch for all the small GEMV work (640 blocks):
//  blocks [0,512):  u[b,e] = sum_d Wa[d,e]*h[b,d]  (block = 64 e x 1 b);
//                   also zeroes awe[b, e0:e0+64] and (e0==0) cb[b]=Wa_b.h[b]
//  blocks [512,640): fused Wp-GEMV + tanh + vp dot: vap[b][chunk] fp64
//                   partials of  sum_d tanh((Wp h)[d]+Wp_b[d]) * vp_w[d]
__global__ void __launch_bounds__(256) k_small(
    const float* __restrict__ Wa, const float* __restrict__ Wp,
    const float* __restrict__ h,  const float* __restrict__ Wa_b,
    const float* __restrict__ Wp_b, const float* __restrict__ vp_w,
    float* __restrict__ u, float* __restrict__ cb,
    double* __restrict__ vap, float* __restrict__ awe) {
    __shared__ float smem[8 * 1024];
    __shared__ double cred[4];
    __shared__ double dpart[4][8];
    const int bid = blockIdx.x;
    if (bid < 512) {
        float* hs   = smem;          // [1024]
        float* part = smem + 1024;   // [4][64]
        const int b  = bid >> 4;
        const int e0 = (bid & 15) * 64;
        ((float4*)hs)[threadIdx.x] = ((const float4*)(h + (size_t)b * ND))[threadIdx.x];
        __syncthreads();
        const int el    = threadIdx.x & 63;
        const int strip = threadIdx.x >> 6;
        const int e     = e0 + el;
        const int d0    = strip * 256;
        float acc = 0.f;
#pragma unroll 8
        for (int dd = 0; dd < 256; ++dd)
            acc = fmaf(Wa[(size_t)(d0 + dd) * NE + e], hs[d0 + dd], acc);
        part[strip * 64 + el] = acc;
        __syncthreads();
        if (threadIdx.x < 64) {
            u[(size_t)b * NE + e0 + threadIdx.x] =
                part[threadIdx.x] + part[64 + threadIdx.x] +
                part[128 + threadIdx.x] + part[192 + threadIdx.x];
            awe[(size_t)b * NE + e0 + threadIdx.x] = 0.f;  // pre-zero for k_finish atomics
        }
        if ((bid & 15) == 0) {       // block-uniform: cb[b] = Wa_b . h[b] (fp64)
            double ca = 0.0;
            for (int d = threadIdx.x; d < ND; d += 256)
                ca += (double)Wa_b[d] * (double)hs[d];
            for (int off = 32; off > 0; off >>= 1) ca += __shfl_down(ca, off);
            if ((threadIdx.x & 63) == 0) cred[threadIdx.x >> 6] = ca;
            __syncthreads();
            if (threadIdx.x == 0) cb[b] = (float)(cred[0] + cred[1] + cred[2] + cred[3]);
        }
    } else {
        float (*hs)[1024] = (float(*)[1024])smem;   // [8][1024]
        const int j     = bid - 512;
        const int b0    = (j >> 5) * 8;
        const int chunk = j & 31;            // 32 d's per chunk
        const float4* h4 = (const float4*)(h + (size_t)b0 * ND);
        float4* hs4 = (float4*)&hs[0][0];
        for (int k = 0; k < 8; ++k) hs4[k * 256 + threadIdx.x] = h4[k * 256 + threadIdx.x];
        __syncthreads();
        const int wave = threadIdx.x >> 6;
        const int lane = threadIdx.x & 63;
        double tacc[8];
#pragma unroll
        for (int bb = 0; bb < 8; ++bb) tacc[bb] = 0.0;
        for (int dd = 0; dd < 8; ++dd) {
            const int d = chunk * 32 + wave * 8 + dd;
            const float* wrow = Wp + (size_t)d * ND;
            float acc[8];
#pragma unroll
            for (int bb = 0; bb < 8; ++bb) acc[bb] = 0.f;
            for (int e = lane; e < ND; e += 64) {
                float w = wrow[e];
#pragma unroll
                for (int bb = 0; bb < 8; ++bb) acc[bb] = fmaf(w, hs[bb][e], acc[bb]);
            }
#pragma unroll
            for (int bb = 0; bb < 8; ++bb) {
                float v = acc[bb];
                for (int off = 32; off > 0; off >>= 1) v += __shfl_down(v, off);
                if (lane == 0)
                    tacc[bb] += tanh((double)v + (double)Wp_b[d]) * (double)vp_w[d];
            }
        }
        if (lane == 0)
#pragma unroll
            for (int bb = 0; bb < 8; ++bb) dpart[wave][bb] = tacc[bb];
        __syncthreads();
        if (threadIdx.x < 8) {
            const int bb = threadIdx.x;
            vap[(size_t)(b0 + bb) * 32 + chunk] =
                dpart[0][bb] + dpart[1][bb] + dpart[2][bb] + dpart[3][bb];
        }
    }
}

// -------------------------------------------------------------------------
// att[b,s] = enc[b,s,:] . u[b] + cb[b]  — the 256 MB pass (BW floor), plus
// per-block softmax partials (m_blk, Z_blk) over its 32 s values.
// grid (NS/32, NB), block 256; 8 rows per wave.
__global__ void __launch_bounds__(256) k_att(const float* __restrict__ enc,
                                             const float* __restrict__ u,
                                             const float* __restrict__ cb,
                                             float* __restrict__ att,
                                             float2* __restrict__ pmz) {
    __shared__ float4 us[256];
    __shared__ float satt[32];
    const int b    = blockIdx.y;
    const int wave = threadIdx.x >> 6, lane = threadIdx.x & 63;
    us[threadIdx.x] = ((const float4*)(u + (size_t)b * NE))[threadIdx.x];
    __syncthreads();
    const float cbv   = cb[b];
    const int  s_base = blockIdx.x * 32 + wave * 8;
#pragma unroll 2
    for (int r = 0; r < 8; ++r) {
        const int s = s_base + r;
        const float4* erow = (const float4*)(enc + ((size_t)b * NS + s) * NE);
        float acc = 0.f;
#pragma unroll
        for (int i = 0; i < 4; ++i) {
            float4 ev = erow[i * 64 + lane];
            float4 uv = us[i * 64 + lane];
            acc += ev.x * uv.x + ev.y * uv.y + ev.z * uv.z + ev.w * uv.w;
        }
        for (int off = 32; off > 0; off >>= 1) acc += __shfl_down(acc, off);
        if (lane == 0) {
            const float v = acc + cbv;
            att[b * NS + s] = v;
            satt[wave * 8 + r] = v;
        }
    }
    __syncthreads();
    if (threadIdx.x < 64) {                       // wave 0 reduces the 32 values
        float a  = (threadIdx.x < 32) ? satt[threadIdx.x] : -3.4e38f;
        float lm = a;
        for (int off = 32; off > 0; off >>= 1) lm = fmaxf(lm, __shfl_down(lm, off));
        lm = __shfl(lm, 0);
        float z = (threadIdx.x < 32) ? expf(a - lm) : 0.f;
        for (int off = 32; off > 0; off >>= 1) z += __shfl_down(z, off);
        if (threadIdx.x == 0) pmz[b * 64 + blockIdx.x] = float2{lm, z};
    }
}

// -------------------------------------------------------------------------
// Per block: reduce pmz -> (m, Z), reduce vap -> pos (fp64), then write its
// 256-s alpha chunk and accumulate its 16 window rows into awe (atomicAdd;
// alpha is exactly 0 in fp32 beyond |s-pos| ~ 29, so 128 rows suffice).
// grid (8, NB), block 256.
__global__ void __launch_bounds__(256) k_finish(
    const float* __restrict__ att, const float2* __restrict__ pmz,
    const double* __restrict__ vap, const float* __restrict__ vp_b,
    const float* __restrict__ enc, float* __restrict__ alpha,
    float* __restrict__ awe) {
    const int b = blockIdx.y, c = blockIdx.x;
    __shared__ float m_sh, z_sh, p_sh;
    __shared__ float asw[16];
    if (threadIdx.x < 64) {
        float2 mz = pmz[b * 64 + threadIdx.x];
        float lm = mz.x;
        for (int off = 32; off > 0; off >>= 1) lm = fmaxf(lm, __shfl_down(lm, off));
        lm = __shfl(lm, 0);
        float z = mz.y * expf(mz.x - lm);
        for (int off = 32; off > 0; off >>= 1) z += __shfl_down(z, off);
        double va = (threadIdx.x < 32) ? vap[(size_t)b * 32 + threadIdx.x] : 0.0;
        for (int off = 32; off > 0; off >>= 1) va += __shfl_down(va, off);
        if (threadIdx.x == 0) {
            m_sh = lm;
            z_sh = z;
            const double vv = va + (double)vp_b[0];
            p_sh = (float)((double)NS / (1.0 + exp(-vv)));
        }
    }
    __syncthreads();
    const float m = m_sh, invZ = 1.f / z_sh, p = p_sh;
    {   // alpha chunk: one s per thread
        const int s = c * 256 + threadIdx.x;
        const float dp = (float)s - p;
        alpha[b * NS + s] = expf(att[b * NS + s] - m - dp * dp * 0.125f) * invZ;
    }
    int s0 = (int)floorf(p) - 63;
    if (s0 < 0) s0 = 0;
    if (s0 > NS - 128) s0 = NS - 128;
    if (threadIdx.x < 16) {
        const int sr = s0 + c * 16 + threadIdx.x;
        const float dp = (float)sr - p;
        asw[threadIdx.x] = expf(att[b * NS + sr] - m - dp * dp * 0.125f) * invZ;
    }
    __syncthreads();
    float4 acc = {0.f, 0.f, 0.f, 0.f};
    const float4* ebase = (const float4*)(enc + ((size_t)b * NS + s0 + c * 16) * NE);
#pragma unroll 4
    for (int r = 0; r < 16; ++r) {
        const float a = asw[r];
        float4 ev = ebase[(size_t)r * 256 + threadIdx.x];
        acc.x = fmaf(a, ev.x, acc.x);
        acc.y = fmaf(a, ev.y, acc.y);
        acc.z = fmaf(a, ev.z, acc.z);
        acc.w = fmaf(a, ev.w, acc.w);
    }
    float* dst = awe + (size_t)b * NE + threadIdx.x * 4;
    atomicAdd(dst + 0, acc.x);
    atomicAdd(dst + 1, acc.y);
    atomicAdd(dst + 2, acc.z);
    atomicAdd(dst + 3, acc.w);
}

// -------------------------------------------------------------------------
extern "C" void kernel_launch(void* const* d_in, const int* in_sizes, int n_in,
                              void* d_out, int out_size, void* d_ws, size_t ws_size,
                              hipStream_t stream) {
    const float* enc  = (const float*)d_in[0];
    const float* h    = (const float*)d_in[1];
    // d_in[2] currentPosition: unused by the reference
    const float* Wa_w = (const float*)d_in[3];
    const float* Wa_b = (const float*)d_in[4];
    const float* Wp_w = (const float*)d_in[5];
    const float* Wp_b = (const float*)d_in[6];
    const float* vp_w = (const float*)d_in[7];
    const float* vp_b = (const float*)d_in[8];

    float* out   = (float*)d_out;
    float* awe   = out;            // [NB*NE]
    float* alpha = out + NB * NE;  // [NB*NS]

    // ws layout (doubles first for 8B alignment)
    double* vap = (double*)d_ws;                 // NB*32 doubles
    float*  u   = (float*)(vap + NB * 32);       // NB*NE
    float*  cb  = u + NB * NE;                   // NB
    float*  att = cb + NB;                       // NB*NS
    float2* pmz = (float2*)(att + NB * NS);      // NB*64 pairs (offset 8B-aligned)

    k_small <<<640, 256, 0, stream>>>(Wa_w, Wp_w, h, Wa_b, Wp_b, vp_w, u, cb, vap, awe);
    k_att   <<<dim3(NS / 32, NB), 256, 0, stream>>>(enc, u, cb, att, pmz);
    k_finish<<<dim3(8, NB), 256, 0, stream>>>(att, pmz, vap, vp_b, enc, alpha, awe);
}

// Round 5
// 445.774 us; speedup vs baseline: 1.0527x; 1.0527x over previous
//
#include <hip/hip_runtime.h>
#include <math.h>

constexpr int NB = 32;
constexpr int NS = 2048;
constexpr int NE = 1024;
constexpr int ND = 1024;

// -------------------------------------------------------------------------
// One dispatch for all the small GEMV work (640 blocks):
//  blocks [0,512):  u[b,e] = sum_d Wa[d,e]*h[b,d]  (block = 64 e x 1 b);
//                   also zeroes awe[b, e0:e0+64] and (e0==0) cb[b]=Wa_b.h[b]
//  blocks [512,640): fused Wp-GEMV + tanh + vp dot: vap[b][chunk] fp64
//                   partials of  sum_d tanh((Wp h)[d]+Wp_b[d]) * vp_w[d].
//                   tanh is PARALLEL (one per thread via LDS staging) — the
//                   R4 lane-0-serial version cost ~10us on the critical path.
__global__ void __launch_bounds__(256) k_small(
    const float* __restrict__ Wa, const float* __restrict__ Wp,
    const float* __restrict__ h,  const float* __restrict__ Wa_b,
    const float* __restrict__ Wp_b, const float* __restrict__ vp_w,
    float* __restrict__ u, float* __restrict__ cb,
    double* __restrict__ vap, float* __restrict__ awe) {
    __shared__ float smem[8 * 1024];
    __shared__ double cred[4];
    __shared__ float vsh[8][32];
    const int bid = blockIdx.x;
    if (bid < 512) {
        float* hs   = smem;          // [1024]
        float* part = smem + 1024;   // [4][64]
        const int b  = bid >> 4;
        const int e0 = (bid & 15) * 64;
        ((float4*)hs)[threadIdx.x] = ((const float4*)(h + (size_t)b * ND))[threadIdx.x];
        __syncthreads();
        const int el    = threadIdx.x & 63;
        const int strip = threadIdx.x >> 6;
        const int e     = e0 + el;
        const int d0    = strip * 256;
        float acc = 0.f;
#pragma unroll 8
        for (int dd = 0; dd < 256; ++dd)
            acc = fmaf(Wa[(size_t)(d0 + dd) * NE + e], hs[d0 + dd], acc);
        part[strip * 64 + el] = acc;
        __syncthreads();
        if (threadIdx.x < 64) {
            u[(size_t)b * NE + e0 + threadIdx.x] =
                part[threadIdx.x] + part[64 + threadIdx.x] +
                part[128 + threadIdx.x] + part[192 + threadIdx.x];
            awe[(size_t)b * NE + e0 + threadIdx.x] = 0.f;  // pre-zero for k_finish atomics
        }
        if ((bid & 15) == 0) {       // block-uniform: cb[b] = Wa_b . h[b] (fp64)
            double ca = 0.0;
            for (int d = threadIdx.x; d < ND; d += 256)
                ca += (double)Wa_b[d] * (double)hs[d];
            for (int off = 32; off > 0; off >>= 1) ca += __shfl_down(ca, off);
            if ((threadIdx.x & 63) == 0) cred[threadIdx.x >> 6] = ca;
            __syncthreads();
            if (threadIdx.x == 0) cb[b] = (float)(cred[0] + cred[1] + cred[2] + cred[3]);
        }
    } else {
        float (*hs)[1024] = (float(*)[1024])smem;   // [8][1024]
        const int j     = bid - 512;
        const int b0    = (j >> 5) * 8;
        const int chunk = j & 31;            // 32 d's per chunk
        const float4* h4 = (const float4*)(h + (size_t)b0 * ND);
        float4* hs4 = (float4*)&hs[0][0];
        for (int k = 0; k < 8; ++k) hs4[k * 256 + threadIdx.x] = h4[k * 256 + threadIdx.x];
        __syncthreads();
        const int wave = threadIdx.x >> 6;
        const int lane = threadIdx.x & 63;
        for (int dd = 0; dd < 8; ++dd) {
            const int d = chunk * 32 + wave * 8 + dd;
            const float* wrow = Wp + (size_t)d * ND;
            float acc[8];
#pragma unroll
            for (int bb = 0; bb < 8; ++bb) acc[bb] = 0.f;
            for (int e = lane; e < ND; e += 64) {
                float w = wrow[e];
#pragma unroll
                for (int bb = 0; bb < 8; ++bb) acc[bb] = fmaf(w, hs[bb][e], acc[bb]);
            }
#pragma unroll
            for (int bb = 0; bb < 8; ++bb) {
                float v = acc[bb];
                for (int off = 32; off > 0; off >>= 1) v += __shfl_down(v, off);
                if (lane == 0) vsh[bb][wave * 8 + dd] = v;   // fp32 pre-activation
            }
        }
        __syncthreads();
        // One fp64 tanh per thread: thread -> (bb = t>>5, dl = t&31).
        const int bb = threadIdx.x >> 5, dl = threadIdx.x & 31;
        const int d  = chunk * 32 + dl;
        double tv = tanh((double)vsh[bb][dl] + (double)Wp_b[d]) * (double)vp_w[d];
        // 32-lane group reduce (groups 32-aligned in wave; offs 16..1 stay in-group
        // for all lanes feeding lane dl==0)
        for (int off = 16; off > 0; off >>= 1) tv += __shfl_down(tv, off);
        if (dl == 0) vap[(size_t)(b0 + bb) * 32 + chunk] = tv;
    }
}

// -------------------------------------------------------------------------
// att[b,s] = enc[b,s,:] . u[b] + cb[b]  — the 256 MB pass (BW floor), plus
// per-block softmax partials (m_blk, Z_blk) over its 32 s values.
// grid (NS/32, NB), block 256; 8 rows per wave.
__global__ void __launch_bounds__(256) k_att(const float* __restrict__ enc,
                                             const float* __restrict__ u,
                                             const float* __restrict__ cb,
                                             float* __restrict__ att,
                                             float2* __restrict__ pmz) {
    __shared__ float4 us[256];
    __shared__ float satt[32];
    const int b    = blockIdx.y;
    const int wave = threadIdx.x >> 6, lane = threadIdx.x & 63;
    us[threadIdx.x] = ((const float4*)(u + (size_t)b * NE))[threadIdx.x];
    __syncthreads();
    const float cbv   = cb[b];
    const int  s_base = blockIdx.x * 32 + wave * 8;
#pragma unroll 2
    for (int r = 0; r < 8; ++r) {
        const int s = s_base + r;
        const float4* erow = (const float4*)(enc + ((size_t)b * NS + s) * NE);
        float acc = 0.f;
#pragma unroll
        for (int i = 0; i < 4; ++i) {
            float4 ev = erow[i * 64 + lane];
            float4 uv = us[i * 64 + lane];
            acc += ev.x * uv.x + ev.y * uv.y + ev.z * uv.z + ev.w * uv.w;
        }
        for (int off = 32; off > 0; off >>= 1) acc += __shfl_down(acc, off);
        if (lane == 0) {
            const float v = acc + cbv;
            att[b * NS + s] = v;
            satt[wave * 8 + r] = v;
        }
    }
    __syncthreads();
    if (threadIdx.x < 64) {                       // wave 0 reduces the 32 values
        float a  = (threadIdx.x < 32) ? satt[threadIdx.x] : -3.4e38f;
        float lm = a;
        for (int off = 32; off > 0; off >>= 1) lm = fmaxf(lm, __shfl_down(lm, off));
        lm = __shfl(lm, 0);
        float z = (threadIdx.x < 32) ? expf(a - lm) : 0.f;
        for (int off = 32; off > 0; off >>= 1) z += __shfl_down(z, off);
        if (threadIdx.x == 0) pmz[b * 64 + blockIdx.x] = float2{lm, z};
    }
}

// -------------------------------------------------------------------------
// Per block: reduce pmz -> (m, Z), reduce vap -> pos (fp64), then write its
// 256-s alpha chunk and accumulate its 16 window rows into awe (atomicAdd;
// alpha is exactly 0 in fp32 beyond |s-pos| ~ 29, so 128 rows suffice).
// grid (8, NB), block 256.
__global__ void __launch_bounds__(256) k_finish(
    const float* __restrict__ att, const float2* __restrict__ pmz,
    const double* __restrict__ vap, const float* __restrict__ vp_b,
    const float* __restrict__ enc, float* __restrict__ alpha,
    float* __restrict__ awe) {
    const int b = blockIdx.y, c = blockIdx.x;
    __shared__ float m_sh, z_sh, p_sh;
    __shared__ float asw[16];
    if (threadIdx.x < 64) {
        float2 mz = pmz[b * 64 + threadIdx.x];
        float lm = mz.x;
        for (int off = 32; off > 0; off >>= 1) lm = fmaxf(lm, __shfl_down(lm, off));
        lm = __shfl(lm, 0);
        float z = mz.y * expf(mz.x - lm);
        for (int off = 32; off > 0; off >>= 1) z += __shfl_down(z, off);
        double va = (threadIdx.x < 32) ? vap[(size_t)b * 32 + threadIdx.x] : 0.0;
        for (int off = 32; off > 0; off >>= 1) va += __shfl_down(va, off);
        if (threadIdx.x == 0) {
            m_sh = lm;
            z_sh = z;
            const double vv = va + (double)vp_b[0];
            p_sh = (float)((double)NS / (1.0 + exp(-vv)));
        }
    }
    __syncthreads();
    const float m = m_sh, invZ = 1.f / z_sh, p = p_sh;
    {   // alpha chunk: one s per thread
        const int s = c * 256 + threadIdx.x;
        const float dp = (float)s - p;
        alpha[b * NS + s] = expf(att[b * NS + s] - m - dp * dp * 0.125f) * invZ;
    }
    int s0 = (int)floorf(p) - 63;
    if (s0 < 0) s0 = 0;
    if (s0 > NS - 128) s0 = NS - 128;
    if (threadIdx.x < 16) {
        const int sr = s0 + c * 16 + threadIdx.x;
        const float dp = (float)sr - p;
        asw[threadIdx.x] = expf(att[b * NS + sr] - m - dp * dp * 0.125f) * invZ;
    }
    __syncthreads();
    float4 acc = {0.f, 0.f, 0.f, 0.f};
    const float4* ebase = (const float4*)(enc + ((size_t)b * NS + s0 + c * 16) * NE);
#pragma unroll 4
    for (int r = 0; r < 16; ++r) {
        const float a = asw[r];
        float4 ev = ebase[(size_t)r * 256 + threadIdx.x];
        acc.x = fmaf(a, ev.x, acc.x);
        acc.y = fmaf(a, ev.y, acc.y);
        acc.z = fmaf(a, ev.z, acc.z);
        acc.w = fmaf(a, ev.w, acc.w);
    }
    float* dst = awe + (size_t)b * NE + threadIdx.x * 4;
    atomicAdd(dst + 0, acc.x);
    atomicAdd(dst + 1, acc.y);
    atomicAdd(dst + 2, acc.z);
    atomicAdd(dst + 3, acc.w);
}

// -------------------------------------------------------------------------
extern "C" void kernel_launch(void* const* d_in, const int* in_sizes, int n_in,
                              void* d_out, int out_size, void* d_ws, size_t ws_size,
                              hipStream_t stream) {
    const float* enc  = (const float*)d_in[0];
    const float* h    = (const float*)d_in[1];
    // d_in[2] currentPosition: unused by the reference
    const float* Wa_w = (const float*)d_in[3];
    const float* Wa_b = (const float*)d_in[4];
    const float* Wp_w = (const float*)d_in[5];
    const float* Wp_b = (const float*)d_in[6];
    const float* vp_w = (const float*)d_in[7];
    const float* vp_b = (const float*)d_in[8];

    float* out   = (float*)d_out;
    float* awe   = out;            // [NB*NE]
    float* alpha = out + NB * NE;  // [NB*NS]

    // ws layout (doubles first for 8B alignment)
    double* vap = (double*)d_ws;                 // NB*32 doubles
    float*  u   = (float*)(vap + NB * 32);       // NB*NE
    float*  cb  = u + NB * NE;                   // NB
    float*  att = cb + NB;                       // NB*NS
    float2* pmz = (float2*)(att + NB * NS);      // NB*64 pairs (offset 8B-aligned)

    k_small <<<640, 256, 0, stream>>>(Wa_w, Wp_w, h, Wa_b, Wp_b, vp_w, u, cb, vap, awe);
    k_att   <<<dim3(NS / 32, NB), 256, 0, stream>>>(enc, u, cb, att, pmz);
    k_finish<<<dim3(8, NB), 256, 0, stream>>>(att, pmz, vap, vp_b, enc, alpha, awe);
}